// Round 8
// baseline (388.809 us; speedup 1.0000x reference)
//
#include <hip/hip_runtime.h>

#define BATCH 32
#define NCAPS 32
#define NR    4608
#define NI    8
#define NO    16
// CSTR = 201: capsule-row stride in LDS floats. 8*CSTR mod 32 = 8, so the cq
// lane bits (lane[1:0]) shift the bank index by 8 -> every consecutive 8-lane
// issue phase covers all 32 banks exactly once (conflict-free ds_read_b128).
// CSTR=200 had 8*200 = 0 mod 32 -> 4-way phase conflicts = 38% of runtime (R7).
#define CSTR  201
#define MAXRB 36
#define L2E   1.44269504088896341f

typedef float f2 __attribute__((ext_vector_type(2)));

// ---------------- fast path ----------------
// 1024 threads: thread = (b-pair w = t>>6, o = (t>>2)&15, c-quarter cq = t&3).
// The b-pair lives in the two halves of packed float2s -> v_pk_fma_f32 halves
// the VALU issue count of the inner loop.
template<int RB, bool FIRST>
__global__ __launch_bounds__(1024, 4) void caps_route_fast(
    const float* __restrict__ x,    // [B][R][I]
    const float* __restrict__ W,    // [C][R][I][O]
    const float* __restrict__ A,    // [B][C][O]
    float* __restrict__ P)          // [nchunk][B][O][C]
{
    __shared__ __align__(16) float Ws[2][NCAPS * CSTR];       // 51.5 KB
    __shared__ __align__(16) f2    xP[RB][BATCH / 2][NI + 1]; // pad: no write conflicts

    const int t  = threadIdx.x;
    const int cq = t & 3;             // c in [8cq, 8cq+8)
    const int o  = (t >> 2) & 15;
    const int w  = t >> 6;            // wave id = b pair
    const int b0 = 2 * w;
    const int r0 = blockIdx.x * RB;

    f2 a2[8];
    if (!FIRST) {
#pragma unroll
        for (int cl = 0; cl < 8; ++cl) {
            a2[cl].x = A[((b0 + 0) * NCAPS + 8 * cq + cl) * NO + o] * L2E;
            a2[cl].y = A[((b0 + 1) * NCAPS + 8 * cq + cl) * NO + o] * L2E;
        }
    }
    f2 acc[8];
#pragma unroll
    for (int cl = 0; cl < 8; ++cl) acc[cl] = (f2)0.f;

    // Stage x pre-interleaved by b-pair: xP[rr][w][i] = {x[2w][i], x[2w+1][i]}.
    for (int s = t; s < RB * (BATCH / 2); s += 1024) {
        const int rr = s >> 4, bp = s & 15;
        const float* xp0 = &x[((size_t)(2 * bp + 0) * NR + r0 + rr) * NI];
        const float* xp1 = &x[((size_t)(2 * bp + 1) * NR + r0 + rr) * NI];
        const float4 a0 = *(const float4*)xp0;
        const float4 a1 = *(const float4*)(xp0 + 4);
        const float4 c0 = *(const float4*)xp1;
        const float4 c1 = *(const float4*)(xp1 + 4);
        f2* d = &xP[rr][bp][0];
        d[0] = f2{a0.x, c0.x}; d[1] = f2{a0.y, c0.y};
        d[2] = f2{a0.z, c0.z}; d[3] = f2{a0.w, c0.w};
        d[4] = f2{a1.x, c1.x}; d[5] = f2{a1.y, c1.y};
        d[6] = f2{a1.z, c1.z}; d[7] = f2{a1.w, c1.w};
    }

    // W staging: 1 float4 per thread per r. c_st = t>>5, part = t&31.
    const int c_st = t >> 5;
    const int part = t & 31;
    const int i_st = part >> 2;
    const int o0   = (part & 3) * 4;
    const float* wsrc = W + ((size_t)c_st * NR + r0) * (NI * NO) + part * 4;

    // Prologue: stage r0 into buf0, prefetch r1.
    {
        const float4 s0 = *(const float4*)wsrc;
        float* d = &Ws[0][c_st * CSTR + o0 * 12 + i_st];
        d[0] = s0.x; d[12] = s0.y; d[24] = s0.z; d[36] = s0.w;
    }
    float4 pf = {};
    if (RB > 1) pf = *(const float4*)(wsrc + NI * NO);
    __syncthreads();

#pragma unroll 1
    for (int rr = 0; rr < RB; ++rr) {
        const int cur = rr & 1;

        // Stage next tile into the other buffer; prefetch rr+2.
        if (rr + 1 < RB) {
            float* d = &Ws[cur ^ 1][c_st * CSTR + o0 * 12 + i_st];
            d[0] = pf.x; d[12] = pf.y; d[24] = pf.z; d[36] = pf.w;
            if (rr + 2 < RB)
                pf = *(const float4*)(wsrc + (size_t)(rr + 2) * (NI * NO));
        }

        // x pair for this wave: wave-uniform broadcast LDS reads.
        f2 xq[NI];
        {
            const f2* xv = &xP[rr][w][0];
#pragma unroll
            for (int i = 0; i < NI; ++i) xq[i] = xv[i];
        }

        const float* wb = &Ws[cur][(8 * cq) * CSTR + o * 12];
        if (FIRST) {
            // A == 0 -> softmax uniform: acc += u (1/32 folded into the store).
#pragma unroll
            for (int cl = 0; cl < 8; ++cl) {
                const float* wp = wb + cl * CSTR;
                const float4 w0 = *(const float4*)wp;
                const float4 w1 = *(const float4*)(wp + 4);
                f2 u2 = xq[0] * w0.x;
                u2 += xq[1] * w0.y;
                u2 += xq[2] * w0.z;
                u2 += xq[3] * w0.w;
                u2 += xq[4] * w1.x;
                u2 += xq[5] * w1.y;
                u2 += xq[6] * w1.z;
                u2 += xq[7] * w1.w;
                acc[cl] += u2;
            }
        } else {
            f2 tt[8];
            f2 Z = (f2)0.f;
#pragma unroll
            for (int cl = 0; cl < 8; ++cl) {
                const float* wp = wb + cl * CSTR;
                const float4 w0 = *(const float4*)wp;
                const float4 w1 = *(const float4*)(wp + 4);
                f2 u2 = xq[0] * w0.x;
                u2 += xq[1] * w0.y;
                u2 += xq[2] * w0.z;
                u2 += xq[3] * w0.w;
                u2 += xq[4] * w1.x;
                u2 += xq[5] * w1.y;
                u2 += xq[6] * w1.z;
                u2 += xq[7] * w1.w;
                // logits bounded (|A|<=3, |u|<~15): exp2 in range without
                // max-subtraction (validated absmax<=1.5e-5 in R3-R7).
                const f2 l2 = u2 * a2[cl];
                f2 e2;
                e2.x = exp2f(l2.x);
                e2.y = exp2f(l2.y);
                Z += e2;
                tt[cl] = e2 * u2;
            }
            // Full Z over 32 c: sum across the 4 cq lanes (lane bits [1:0]).
            Z.x += __shfl_xor(Z.x, 1); Z.x += __shfl_xor(Z.x, 2);
            Z.y += __shfl_xor(Z.y, 1); Z.y += __shfl_xor(Z.y, 2);
            f2 rz;
            rz.x = __builtin_amdgcn_rcpf(Z.x);
            rz.y = __builtin_amdgcn_rcpf(Z.y);
#pragma unroll
            for (int cl = 0; cl < 8; ++cl)
                acc[cl] += tt[cl] * rz;
        }
        __syncthreads();
    }

    // Epilogue: P[blk][b][o][8cq..8cq+7] for both b's of the pair.
#pragma unroll
    for (int bb = 0; bb < 2; ++bb) {
        float* pout = P + (((size_t)blockIdx.x * BATCH + b0 + bb) * NO + o) * NCAPS + 8 * cq;
        float4 v0, v1;
        v0.x = bb ? acc[0].y : acc[0].x; v0.y = bb ? acc[1].y : acc[1].x;
        v0.z = bb ? acc[2].y : acc[2].x; v0.w = bb ? acc[3].y : acc[3].x;
        v1.x = bb ? acc[4].y : acc[4].x; v1.y = bb ? acc[5].y : acc[5].x;
        v1.z = bb ? acc[6].y : acc[6].x; v1.w = bb ? acc[7].y : acc[7].x;
        if (FIRST) {
            v0.x *= 0.03125f; v0.y *= 0.03125f; v0.z *= 0.03125f; v0.w *= 0.03125f;
            v1.x *= 0.03125f; v1.y *= 0.03125f; v1.z *= 0.03125f; v1.w *= 0.03125f;
        }
        *(float4*)pout = v0;
        *(float4*)(pout + 4) = v1;
    }
}

// Stage-1 reduce: coalesced float4 column sums of P[256][16384] -> P2[16][16384].
__global__ __launch_bounds__(256) void caps_partial(const float* __restrict__ P,
                                                    float* __restrict__ P2)
{
    const int tid = threadIdx.x;
    const int ct  = blockIdx.x & 15;      // column tile (1024 floats)
    const int rg  = blockIdx.x >> 4;      // row group (16 rows)
    const size_t col = (size_t)ct * 1024 + tid * 4;
    const float* p = P + (size_t)rg * 16 * 16384 + col;
    float4 s = {0.f, 0.f, 0.f, 0.f};
#pragma unroll
    for (int k = 0; k < 16; ++k) {
        const float4 v = *(const float4*)(p + (size_t)k * 16384);
        s.x += v.x; s.y += v.y; s.z += v.z; s.w += v.w;
    }
    *(float4*)(P2 + (size_t)rg * 16384 + col) = s;
}

// Reduce partials over chunks, squash, update A; emit V on the final iteration.
// P layout [chunk][b][o][c].
__global__ void caps_reduce_squash(const float* __restrict__ P,
                                   float* __restrict__ A,
                                   float* __restrict__ out,
                                   int nchunk)
{
    __shared__ float sm[256];
    const int bc  = blockIdx.x;     // b*NCAPS + c
    const int b   = bc >> 5;
    const int c   = bc & 31;
    const int tid = threadIdx.x;    // 256 = 16 j x 16 o
    const int o = tid & 15;
    const int j = tid >> 4;
    float s = 0.f;
    for (int tch = j; tch < nchunk; tch += 16)
        s += P[(((size_t)tch * BATCH + b) * NO + o) * NCAPS + c];
    sm[tid] = s;
    __syncthreads();
    if (tid < 16) {
        float S = 0.f;
#pragma unroll
        for (int k = 0; k < 16; ++k) S += sm[tid + 16 * k];
        float sq = S * S;
#pragma unroll
        for (int d = 8; d >= 1; d >>= 1) sq += __shfl_xor(sq, d, 16);
        const float scale = sq / ((1.f + sq) * sqrtf(sq));
        const float V = S * scale;
        const int idx = bc * NO + tid;
        A[idx] += V;
        if (out) out[idx] = V;
    }
}

// ---------------- generic fallback (R6 structure, validated) ----------------
__global__ __launch_bounds__(512, 2) void caps_route_generic(
    const float* __restrict__ x, const float* __restrict__ W,
    const float* __restrict__ A, float* __restrict__ P, int rb)
{
    __shared__ __align__(16) float Ws[NCAPS * CSTR];
    __shared__ __align__(16) float xsT[NI * MAXRB * BATCH];

    const int t = threadIdx.x;
    const int b = t & 31;
    const int o = t >> 5;
    const int r0 = blockIdx.x * rb;
    const int rbs = rb * BATCH;

    float a2s[NCAPS];
#pragma unroll
    for (int c = 0; c < NCAPS; ++c)
        a2s[c] = A[(b * NCAPS + c) * NO + o] * L2E;
    float acc[NCAPS];
#pragma unroll
    for (int c = 0; c < NCAPS; ++c) acc[c] = 0.f;

    for (int s = t; s < rbs; s += 512) {
        const int rr = s >> 5, bb = s & 31;
        const float4 v0 = *(const float4*)&x[((size_t)bb * NR + r0 + rr) * NI];
        const float4 v1 = *(const float4*)&x[((size_t)bb * NR + r0 + rr) * NI + 4];
        const float tmp[8] = {v0.x, v0.y, v0.z, v0.w, v1.x, v1.y, v1.z, v1.w};
#pragma unroll
        for (int i = 0; i < NI; ++i) xsT[i * rbs + s] = tmp[i];
    }

    const int cs  = t >> 4;
    const int seg = t & 15;
    const int iw  = seg >> 1;
    const int ob  = (seg & 1) * 8;
    const float* wsrc = W + ((size_t)cs * NR + r0) * (NI * NO) + seg * 8;
    float4 pf0 = *(const float4*)wsrc;
    float4 pf1 = *(const float4*)(wsrc + 4);

    for (int rr = 0; rr < rb; ++rr) {
        __syncthreads();
        {
            const float tmp[8] = {pf0.x, pf0.y, pf0.z, pf0.w,
                                  pf1.x, pf1.y, pf1.z, pf1.w};
#pragma unroll
            for (int k = 0; k < 8; ++k)
                Ws[cs * CSTR + (ob + k) * 12 + iw] = tmp[k];
        }
        if (rr + 1 < rb) {
            wsrc += NI * NO;
            pf0 = *(const float4*)wsrc;
            pf1 = *(const float4*)(wsrc + 4);
        }
        __syncthreads();

        float xq[NI];
#pragma unroll
        for (int i = 0; i < NI; ++i) xq[i] = xsT[i * rbs + rr * 32 + b];

        float tt[NCAPS];
        float Z = 0.f;
        const float* bp = &Ws[o * 12];
#pragma unroll
        for (int c = 0; c < NCAPS; ++c) {
            const float* wp = bp + c * CSTR;
            const float4 w0 = *(const float4*)wp;
            const float4 w1 = *(const float4*)(wp + 4);
            float uu =      xq[0] * w0.x;
            uu = fmaf(xq[1], w0.y, uu);
            uu = fmaf(xq[2], w0.z, uu);
            uu = fmaf(xq[3], w0.w, uu);
            uu = fmaf(xq[4], w1.x, uu);
            uu = fmaf(xq[5], w1.y, uu);
            uu = fmaf(xq[6], w1.z, uu);
            uu = fmaf(xq[7], w1.w, uu);
            const float ee = exp2f(uu * a2s[c]);
            Z += ee;
            tt[c] = ee * uu;
        }
        const float rz = __builtin_amdgcn_rcpf(Z);
#pragma unroll
        for (int c = 0; c < NCAPS; ++c)
            acc[c] = fmaf(tt[c], rz, acc[c]);
    }

    float* pout = P + (((size_t)blockIdx.x * BATCH + b) * NO + o) * NCAPS;
#pragma unroll
    for (int q = 0; q < NCAPS / 4; ++q) {
        float4 v;
        v.x = acc[4 * q + 0]; v.y = acc[4 * q + 1];
        v.z = acc[4 * q + 2]; v.w = acc[4 * q + 3];
        *(float4*)(pout + 4 * q) = v;
    }
}

__global__ void caps_zero(float* __restrict__ p, int n)
{
    const int i = blockIdx.x * blockDim.x + threadIdx.x;
    if (i < n) p[i] = 0.f;
}

extern "C" void kernel_launch(void* const* d_in, const int* in_sizes, int n_in,
                              void* d_out, int out_size, void* d_ws, size_t ws_size,
                              hipStream_t stream)
{
    const float* x = (const float*)d_in[0];   // [32][4608][8]
    const float* W = (const float*)d_in[1];   // [32][4608][8][16]
    float* out = (float*)d_out;               // [32][32][16]

    float* A  = (float*)d_ws;                 // 16384 floats
    float* P  = A + BATCH * NCAPS * NO;       // 256 * 16384 floats
    float* P2 = P + (size_t)256 * BATCH * NCAPS * NO;   // 16 * 16384 floats

    const size_t elem = (size_t)BATCH * NCAPS * NO;   // 16384
    caps_zero<<<(int)((elem + 255) / 256), 256, 0, stream>>>(A, (int)elem);

    if ((1 + 256 + 16) * elem * sizeof(float) <= ws_size) {
        // Fast path: nchunk=256 (1 block/CU), RB=18, two-stage reduce.
        caps_route_fast<18, true><<<256, 1024, 0, stream>>>(x, W, A, P);
        caps_partial<<<256, 256, 0, stream>>>(P, P2);
        caps_reduce_squash<<<BATCH * NCAPS, 256, 0, stream>>>(P2, A, nullptr, 16);
        caps_route_fast<18, false><<<256, 1024, 0, stream>>>(x, W, A, P);
        caps_partial<<<256, 256, 0, stream>>>(P, P2);
        caps_reduce_squash<<<BATCH * NCAPS, 256, 0, stream>>>(P2, A, nullptr, 16);
        caps_route_fast<18, false><<<256, 1024, 0, stream>>>(x, W, A, P);
        caps_partial<<<256, 256, 0, stream>>>(P, P2);
        caps_reduce_squash<<<BATCH * NCAPS, 256, 0, stream>>>(P2, A, out, 16);
    } else {
        int nchunk = 128;
        while (nchunk > 32 &&
               (size_t)(nchunk + 1) * elem * sizeof(float) > ws_size)
            nchunk >>= 1;
        const int rb = NR / nchunk;
        for (int it = 0; it < 3; ++it) {
            caps_route_generic<<<nchunk, 512, 0, stream>>>(x, W, A, P, rb);
            caps_reduce_squash<<<BATCH * NCAPS, 256, 0, stream>>>(
                P, A, it == 2 ? out : nullptr, nchunk);
        }
    }
}

// Round 9
// 154.193 us; speedup vs baseline: 2.5216x; 2.5216x over previous
//
#include <hip/hip_runtime.h>

#define BATCH 32
#define NCAPS 32
#define NR    4608
#define NI    8
#define NO    16
// CSTR = 200 floats (800B): 16B-aligned rows -> ds_read_b128 stays b128.
// Bank decorrelation comes from the row-slot PERMUTATION sigma(c) = 4*(c&7)+(c>>3):
// read addr = (4cl+cq)*200 + 12o; 200 = 8 mod 32 -> start bank = (8cq+12o) mod 32,
// and each 8-lane issue phase (fixed cl, 2 o's x 4 cq) covers all 32 banks once.
// (CSTR=201 killed conflicts but broke 16B alignment -> 4x b32 splits, R8 2x slower.)
#define CSTR  200
#define MAXRB 36
#define L2E   1.44269504088896341f

typedef float f2 __attribute__((ext_vector_type(2)));

// ---------------- fast path ----------------
// 1024 threads: thread = (b-pair w = t>>6, o = (t>>2)&15, c-quarter cq = t&3).
// The b-pair lives in the two halves of packed float2s (v_pk_fma_f32).
template<int RB, bool FIRST>
__global__ __launch_bounds__(1024, 4) void caps_route_fast(
    const float* __restrict__ x,    // [B][R][I]
    const float* __restrict__ W,    // [C][R][I][O]
    const float* __restrict__ A,    // [B][C][O]
    float* __restrict__ P)          // [nchunk][B][O][C]
{
    __shared__ __align__(16) float Ws[2][NCAPS * CSTR];       // 51.2 KB
    __shared__ __align__(16) f2    xP[RB][BATCH / 2][NI + 1]; // padded: no write conflicts

    const int t  = threadIdx.x;
    const int cq = t & 3;             // c in [8cq, 8cq+8)
    const int o  = (t >> 2) & 15;
    const int w  = t >> 6;            // wave id = b pair
    const int b0 = 2 * w;
    const int r0 = blockIdx.x * RB;

    f2 a2[8];
    if (!FIRST) {
#pragma unroll
        for (int cl = 0; cl < 8; ++cl) {
            a2[cl].x = A[((b0 + 0) * NCAPS + 8 * cq + cl) * NO + o] * L2E;
            a2[cl].y = A[((b0 + 1) * NCAPS + 8 * cq + cl) * NO + o] * L2E;
        }
    }
    f2 acc[8];
#pragma unroll
    for (int cl = 0; cl < 8; ++cl) acc[cl] = (f2)0.f;

    // Stage x pre-interleaved by b-pair: xP[rr][w][i] = {x[2w][i], x[2w+1][i]}.
    for (int s = t; s < RB * (BATCH / 2); s += 1024) {
        const int rr = s >> 4, bp = s & 15;
        const float* xp0 = &x[((size_t)(2 * bp + 0) * NR + r0 + rr) * NI];
        const float* xp1 = &x[((size_t)(2 * bp + 1) * NR + r0 + rr) * NI];
        const float4 a0 = *(const float4*)xp0;
        const float4 a1 = *(const float4*)(xp0 + 4);
        const float4 c0 = *(const float4*)xp1;
        const float4 c1 = *(const float4*)(xp1 + 4);
        f2* d = &xP[rr][bp][0];
        d[0] = f2{a0.x, c0.x}; d[1] = f2{a0.y, c0.y};
        d[2] = f2{a0.z, c0.z}; d[3] = f2{a0.w, c0.w};
        d[4] = f2{a1.x, c1.x}; d[5] = f2{a1.y, c1.y};
        d[6] = f2{a1.z, c1.z}; d[7] = f2{a1.w, c1.w};
    }

    // W staging: 1 float4 per thread per r; capsule c_st lands in row slot
    // sigma(c_st) = 4*(c_st&7) + (c_st>>3)  (the bank-decorrelating permutation).
    const int c_st = t >> 5;
    const int sl   = 4 * (c_st & 7) + (c_st >> 3);
    const int part = t & 31;
    const int i_st = part >> 2;
    const int o0   = (part & 3) * 4;
    const float* wsrc = W + ((size_t)c_st * NR + r0) * (NI * NO) + part * 4;

    // Prologue: stage r0 into buf0, prefetch r1.
    {
        const float4 s0 = *(const float4*)wsrc;
        float* d = &Ws[0][sl * CSTR + o0 * 12 + i_st];
        d[0] = s0.x; d[12] = s0.y; d[24] = s0.z; d[36] = s0.w;
    }
    float4 pf = {};
    if (RB > 1) pf = *(const float4*)(wsrc + NI * NO);
    __syncthreads();

#pragma unroll 1
    for (int rr = 0; rr < RB; ++rr) {
        const int cur = rr & 1;

        // Stage next tile into the other buffer; prefetch rr+2.
        if (rr + 1 < RB) {
            float* d = &Ws[cur ^ 1][sl * CSTR + o0 * 12 + i_st];
            d[0] = pf.x; d[12] = pf.y; d[24] = pf.z; d[36] = pf.w;
            if (rr + 2 < RB)
                pf = *(const float4*)(wsrc + (size_t)(rr + 2) * (NI * NO));
        }

        // x pair for this wave: wave-uniform broadcast LDS reads.
        f2 xq[NI];
        {
            const f2* xv = &xP[rr][w][0];
#pragma unroll
            for (int i = 0; i < NI; ++i) xq[i] = xv[i];
        }

        // Capsule 8cq+cl lives at slot 4cl+cq.
        const float* wb = &Ws[cur][cq * CSTR + o * 12];
        if (FIRST) {
            // A == 0 -> softmax uniform: acc += u (1/32 folded into the store).
#pragma unroll
            for (int cl = 0; cl < 8; ++cl) {
                const float* wp = wb + cl * (4 * CSTR);
                const float4 w0 = *(const float4*)wp;
                const float4 w1 = *(const float4*)(wp + 4);
                f2 u2 = xq[0] * w0.x;
                u2 += xq[1] * w0.y;
                u2 += xq[2] * w0.z;
                u2 += xq[3] * w0.w;
                u2 += xq[4] * w1.x;
                u2 += xq[5] * w1.y;
                u2 += xq[6] * w1.z;
                u2 += xq[7] * w1.w;
                acc[cl] += u2;
            }
        } else {
            f2 tt[8];
            f2 Z = (f2)0.f;
#pragma unroll
            for (int cl = 0; cl < 8; ++cl) {
                const float* wp = wb + cl * (4 * CSTR);
                const float4 w0 = *(const float4*)wp;
                const float4 w1 = *(const float4*)(wp + 4);
                f2 u2 = xq[0] * w0.x;
                u2 += xq[1] * w0.y;
                u2 += xq[2] * w0.z;
                u2 += xq[3] * w0.w;
                u2 += xq[4] * w1.x;
                u2 += xq[5] * w1.y;
                u2 += xq[6] * w1.z;
                u2 += xq[7] * w1.w;
                // logits bounded (|A|<=3, |u|<~15): exp2 in range without
                // max-subtraction (validated absmax<=1.5e-5 in R3-R8).
                const f2 l2 = u2 * a2[cl];
                f2 e2;
                e2.x = exp2f(l2.x);
                e2.y = exp2f(l2.y);
                Z += e2;
                tt[cl] = e2 * u2;
            }
            // Full Z over 32 c: sum across the 4 cq lanes (lane bits [1:0]).
            Z.x += __shfl_xor(Z.x, 1); Z.x += __shfl_xor(Z.x, 2);
            Z.y += __shfl_xor(Z.y, 1); Z.y += __shfl_xor(Z.y, 2);
            f2 rz;
            rz.x = __builtin_amdgcn_rcpf(Z.x);
            rz.y = __builtin_amdgcn_rcpf(Z.y);
#pragma unroll
            for (int cl = 0; cl < 8; ++cl)
                acc[cl] += tt[cl] * rz;
        }
        __syncthreads();
    }

    // Epilogue: P[blk][b][o][8cq..8cq+7] for both b's of the pair.
#pragma unroll
    for (int bb = 0; bb < 2; ++bb) {
        float* pout = P + (((size_t)blockIdx.x * BATCH + b0 + bb) * NO + o) * NCAPS + 8 * cq;
        float4 v0, v1;
        v0.x = bb ? acc[0].y : acc[0].x; v0.y = bb ? acc[1].y : acc[1].x;
        v0.z = bb ? acc[2].y : acc[2].x; v0.w = bb ? acc[3].y : acc[3].x;
        v1.x = bb ? acc[4].y : acc[4].x; v1.y = bb ? acc[5].y : acc[5].x;
        v1.z = bb ? acc[6].y : acc[6].x; v1.w = bb ? acc[7].y : acc[7].x;
        if (FIRST) {
            v0.x *= 0.03125f; v0.y *= 0.03125f; v0.z *= 0.03125f; v0.w *= 0.03125f;
            v1.x *= 0.03125f; v1.y *= 0.03125f; v1.z *= 0.03125f; v1.w *= 0.03125f;
        }
        *(float4*)pout = v0;
        *(float4*)(pout + 4) = v1;
    }
}

// Stage-1 reduce: coalesced float4 column sums of P[256][16384] -> P2[16][16384].
__global__ __launch_bounds__(256) void caps_partial(const float* __restrict__ P,
                                                    float* __restrict__ P2)
{
    const int tid = threadIdx.x;
    const int ct  = blockIdx.x & 15;      // column tile (1024 floats)
    const int rg  = blockIdx.x >> 4;      // row group (16 rows)
    const size_t col = (size_t)ct * 1024 + tid * 4;
    const float* p = P + (size_t)rg * 16 * 16384 + col;
    float4 s = {0.f, 0.f, 0.f, 0.f};
#pragma unroll
    for (int k = 0; k < 16; ++k) {
        const float4 v = *(const float4*)(p + (size_t)k * 16384);
        s.x += v.x; s.y += v.y; s.z += v.z; s.w += v.w;
    }
    *(float4*)(P2 + (size_t)rg * 16384 + col) = s;
}

// Reduce partials over chunks, squash, update A; emit V on the final iteration.
// P layout [chunk][b][o][c].
__global__ void caps_reduce_squash(const float* __restrict__ P,
                                   float* __restrict__ A,
                                   float* __restrict__ out,
                                   int nchunk)
{
    __shared__ float sm[256];
    const int bc  = blockIdx.x;     // b*NCAPS + c
    const int b   = bc >> 5;
    const int c   = bc & 31;
    const int tid = threadIdx.x;    // 256 = 16 j x 16 o
    const int o = tid & 15;
    const int j = tid >> 4;
    float s = 0.f;
    for (int tch = j; tch < nchunk; tch += 16)
        s += P[(((size_t)tch * BATCH + b) * NO + o) * NCAPS + c];
    sm[tid] = s;
    __syncthreads();
    if (tid < 16) {
        float S = 0.f;
#pragma unroll
        for (int k = 0; k < 16; ++k) S += sm[tid + 16 * k];
        float sq = S * S;
#pragma unroll
        for (int d = 8; d >= 1; d >>= 1) sq += __shfl_xor(sq, d, 16);
        const float scale = sq / ((1.f + sq) * sqrtf(sq));
        const float V = S * scale;
        const int idx = bc * NO + tid;
        A[idx] += V;
        if (out) out[idx] = V;
    }
}

// ---------------- generic fallback (R6 structure, validated) ----------------
__global__ __launch_bounds__(512, 2) void caps_route_generic(
    const float* __restrict__ x, const float* __restrict__ W,
    const float* __restrict__ A, float* __restrict__ P, int rb)
{
    __shared__ __align__(16) float Ws[NCAPS * CSTR];
    __shared__ __align__(16) float xsT[NI * MAXRB * BATCH];

    const int t = threadIdx.x;
    const int b = t & 31;
    const int o = t >> 5;
    const int r0 = blockIdx.x * rb;
    const int rbs = rb * BATCH;

    float a2s[NCAPS];
#pragma unroll
    for (int c = 0; c < NCAPS; ++c)
        a2s[c] = A[(b * NCAPS + c) * NO + o] * L2E;
    float acc[NCAPS];
#pragma unroll
    for (int c = 0; c < NCAPS; ++c) acc[c] = 0.f;

    for (int s = t; s < rbs; s += 512) {
        const int rr = s >> 5, bb = s & 31;
        const float4 v0 = *(const float4*)&x[((size_t)bb * NR + r0 + rr) * NI];
        const float4 v1 = *(const float4*)&x[((size_t)bb * NR + r0 + rr) * NI + 4];
        const float tmp[8] = {v0.x, v0.y, v0.z, v0.w, v1.x, v1.y, v1.z, v1.w};
#pragma unroll
        for (int i = 0; i < NI; ++i) xsT[i * rbs + s] = tmp[i];
    }

    const int cs  = t >> 4;
    const int seg = t & 15;
    const int iw  = seg >> 1;
    const int ob  = (seg & 1) * 8;
    const float* wsrc = W + ((size_t)cs * NR + r0) * (NI * NO) + seg * 8;
    float4 pf0 = *(const float4*)wsrc;
    float4 pf1 = *(const float4*)(wsrc + 4);

    for (int rr = 0; rr < rb; ++rr) {
        __syncthreads();
        {
            const float tmp[8] = {pf0.x, pf0.y, pf0.z, pf0.w,
                                  pf1.x, pf1.y, pf1.z, pf1.w};
#pragma unroll
            for (int k = 0; k < 8; ++k)
                Ws[cs * CSTR + (ob + k) * 12 + iw] = tmp[k];
        }
        if (rr + 1 < rb) {
            wsrc += NI * NO;
            pf0 = *(const float4*)wsrc;
            pf1 = *(const float4*)(wsrc + 4);
        }
        __syncthreads();

        float xq[NI];
#pragma unroll
        for (int i = 0; i < NI; ++i) xq[i] = xsT[i * rbs + rr * 32 + b];

        float tt[NCAPS];
        float Z = 0.f;
        const float* bp = &Ws[o * 12];
#pragma unroll
        for (int c = 0; c < NCAPS; ++c) {
            const float* wp = bp + c * CSTR;
            const float4 w0 = *(const float4*)wp;
            const float4 w1 = *(const float4*)(wp + 4);
            float uu =      xq[0] * w0.x;
            uu = fmaf(xq[1], w0.y, uu);
            uu = fmaf(xq[2], w0.z, uu);
            uu = fmaf(xq[3], w0.w, uu);
            uu = fmaf(xq[4], w1.x, uu);
            uu = fmaf(xq[5], w1.y, uu);
            uu = fmaf(xq[6], w1.z, uu);
            uu = fmaf(xq[7], w1.w, uu);
            const float ee = exp2f(uu * a2s[c]);
            Z += ee;
            tt[c] = ee * uu;
        }
        const float rz = __builtin_amdgcn_rcpf(Z);
#pragma unroll
        for (int c = 0; c < NCAPS; ++c)
            acc[c] = fmaf(tt[c], rz, acc[c]);
    }

    float* pout = P + (((size_t)blockIdx.x * BATCH + b) * NO + o) * NCAPS;
#pragma unroll
    for (int q = 0; q < NCAPS / 4; ++q) {
        float4 v;
        v.x = acc[4 * q + 0]; v.y = acc[4 * q + 1];
        v.z = acc[4 * q + 2]; v.w = acc[4 * q + 3];
        *(float4*)(pout + 4 * q) = v;
    }
}

__global__ void caps_zero(float* __restrict__ p, int n)
{
    const int i = blockIdx.x * blockDim.x + threadIdx.x;
    if (i < n) p[i] = 0.f;
}

extern "C" void kernel_launch(void* const* d_in, const int* in_sizes, int n_in,
                              void* d_out, int out_size, void* d_ws, size_t ws_size,
                              hipStream_t stream)
{
    const float* x = (const float*)d_in[0];   // [32][4608][8]
    const float* W = (const float*)d_in[1];   // [32][4608][8][16]
    float* out = (float*)d_out;               // [32][32][16]

    float* A  = (float*)d_ws;                 // 16384 floats
    float* P  = A + BATCH * NCAPS * NO;       // 256 * 16384 floats
    float* P2 = P + (size_t)256 * BATCH * NCAPS * NO;   // 16 * 16384 floats

    const size_t elem = (size_t)BATCH * NCAPS * NO;   // 16384
    caps_zero<<<(int)((elem + 255) / 256), 256, 0, stream>>>(A, (int)elem);

    if ((1 + 256 + 16) * elem * sizeof(float) <= ws_size) {
        // Fast path: nchunk=256 (1 block/CU), RB=18, two-stage reduce.
        caps_route_fast<18, true><<<256, 1024, 0, stream>>>(x, W, A, P);
        caps_partial<<<256, 256, 0, stream>>>(P, P2);
        caps_reduce_squash<<<BATCH * NCAPS, 256, 0, stream>>>(P2, A, nullptr, 16);
        caps_route_fast<18, false><<<256, 1024, 0, stream>>>(x, W, A, P);
        caps_partial<<<256, 256, 0, stream>>>(P, P2);
        caps_reduce_squash<<<BATCH * NCAPS, 256, 0, stream>>>(P2, A, nullptr, 16);
        caps_route_fast<18, false><<<256, 1024, 0, stream>>>(x, W, A, P);
        caps_partial<<<256, 256, 0, stream>>>(P, P2);
        caps_reduce_squash<<<BATCH * NCAPS, 256, 0, stream>>>(P2, A, out, 16);
    } else {
        int nchunk = 128;
        while (nchunk > 32 &&
               (size_t)(nchunk + 1) * elem * sizeof(float) > ws_size)
            nchunk >>= 1;
        const int rb = NR / nchunk;
        for (int it = 0; it < 3; ++it) {
            caps_route_generic<<<nchunk, 512, 0, stream>>>(x, W, A, P, rb);
            caps_reduce_squash<<<BATCH * NCAPS, 256, 0, stream>>>(
                P, A, it == 2 ? out : nullptr, nchunk);
        }
    }
}